// Round 3
// baseline (227.786 us; speedup 1.0000x reference)
//
#include <hip/hip_runtime.h>

typedef unsigned int   u32;
typedef unsigned short u16;
typedef short bf16x8 __attribute__((ext_vector_type(8)));
typedef float f32x4  __attribute__((ext_vector_type(4)));

#define GAS(p) ((const __attribute__((address_space(1))) void*)(p))
#define LAS(p) ((__attribute__((address_space(3))) void*)(p))

__device__ __forceinline__ u16 f2bf(float f) {
  union { float f; u32 u; } v; v.f = f;
  u32 r = v.u + 0x7fffu + ((v.u >> 16) & 1u);
  return (u16)(r >> 16);
}
__device__ __forceinline__ u32 pack2(float a, float b) {
  return (u32)f2bf(a) | ((u32)f2bf(b) << 16);
}

// ---------------- unified f32 -> bf16 convert (all 5 inputs, 1 launch) -------
__global__ __launch_bounds__(256) void cvt_all(
    const float* __restrict__ q,  const float* __restrict__ wq,
    const float* __restrict__ wk, const float* __restrict__ wv,
    const float* __restrict__ wo, u16* __restrict__ xb,
    u16* __restrict__ wqkb, u16* __restrict__ wvb, u16* __restrict__ wob) {
  const int b = blockIdx.x;
  const float* src; u16* dst; long off;
  if (b < 2048)      { src = q;  dst = xb;             off = (long)b * 2048; }
  else if (b < 2560) { src = wq; dst = wqkb;           off = (long)(b - 2048) * 2048; }
  else if (b < 3072) { src = wk; dst = wqkb + 1048576; off = (long)(b - 2560) * 2048; }
  else if (b < 3584) { src = wv; dst = wvb;            off = (long)(b - 3072) * 2048; }
  else               { src = wo; dst = wob;            off = (long)(b - 3584) * 2048; }
  const long i = off + (long)threadIdx.x * 8;
  const float4* xp = (const float4*)(src + i);
  float4 a = xp[0], c = xp[1];
  uint4 o;
  o.x = pack2(a.x, a.y); o.y = pack2(a.z, a.w);
  o.z = pack2(c.x, c.y); o.w = pack2(c.z, c.w);
  *(uint4*)(dst + i) = o;
}

// ---------------- bf16 GEMM: C = A @ Bt^T (+epilogue) ----------------
// A [M][K] row-major bf16 (lda), Bt [N][K] row-major bf16 (ldb).
// 128x128 tile, BK=64, 4 waves (2x2), mfma_f32_16x16x32_bf16.
// Double-buffered LDS 2-phase (T3 minimum recipe): issue next tile's
// global_load_lds BEFORE computing current tile; ONE __syncthreads (which
// drains vmcnt) per K-tile. Staging latency hides under the 128 MFMAs —
// critical for our 256-block grids that run at 1 block/CU.
// LDS XOR-swizzle (slot ^= row&7) via pre-swizzled global source
// (global_load_lds writes linearly) + swizzled ds_read (guide §5/G4, rule 21).
#define EPI_QK_SPLIT_BF16 0
#define EPI_BIAS_ROW_BF16 1
#define EPI_SCALE_F32     2
#define EPI_BIAS_COL_F32  3
#define EPI_RESHAPE_BF16  4

template <int EPI>
__global__ __launch_bounds__(256, 2)
void gemm_bt(const u16* __restrict__ A, long sAz, int lda,
             const u16* __restrict__ Bt, long sBz, int ldb,
             void* __restrict__ Cv, void* __restrict__ Cv2, long sCz, int ldc,
             const float* __restrict__ bias, const float* __restrict__ bias2,
             float scale, int kTiles) {
  __shared__ __align__(16) u16 As[2][128 * 64];
  __shared__ __align__(16) u16 Bs[2][128 * 64];

  const int tid = threadIdx.x, lane = tid & 63, wid = tid >> 6;
  const int wm = wid >> 1, wn = wid & 1;
  const long tm = (long)blockIdx.x * 128, tn = (long)blockIdx.y * 128;
  const u16* Ab = A + (long)blockIdx.z * sAz;
  const u16* Bb = Bt + (long)blockIdx.z * sBz;

  const int rl = lane >> 3;        // row within 8-row stripe this lane stages
  const int sl = (lane & 7) ^ rl;  // pre-swizzled logical 16B-slot index
  const int fr = lane & 15;        // fragment row (A) / col (B)
  const int fq = lane >> 4;        // k-quarter 0..3

  // per-lane global addresses for staging (row stripe this lane serves)
  const long arow = tm + wid * 8 + rl;   // + i*32
  const long brow = tn + wid * 8 + rl;

  f32x4 acc[4][4] = {};

#define STAGE(buf, kt_)                                                          \
  {                                                                              \
    const int k0_ = (kt_) * 64;                                                  \
    _Pragma("unroll")                                                            \
    for (int i = 0; i < 4; ++i) {                                                \
      const u16* g = Ab + (arow + i * 32) * (long)lda + k0_ + sl * 8;            \
      __builtin_amdgcn_global_load_lds(GAS(g),                                   \
          LAS(As[buf] + (i * 32 + wid * 8) * 64), 16, 0, 0);                     \
    }                                                                            \
    _Pragma("unroll")                                                            \
    for (int i = 0; i < 4; ++i) {                                                \
      const u16* g = Bb + (brow + i * 32) * (long)ldb + k0_ + sl * 8;            \
      __builtin_amdgcn_global_load_lds(GAS(g),                                   \
          LAS(Bs[buf] + (i * 32 + wid * 8) * 64), 16, 0, 0);                     \
    }                                                                            \
  }

  STAGE(0, 0);
  __syncthreads();  // drain vmcnt: buf0 ready

  int cur = 0;
  for (int kt = 0; kt < kTiles; ++kt) {
    if (kt + 1 < kTiles) STAGE(cur ^ 1, kt + 1);  // prefetch next (overlaps MFMA)
    const u16* Asc = As[cur];
    const u16* Bsc = Bs[cur];
#pragma unroll
    for (int ks = 0; ks < 2; ++ks) {
      bf16x8 af[4], bfr[4];
#pragma unroll
      for (int mt = 0; mt < 4; ++mt) {
        int row = wm * 64 + mt * 16 + fr;
        int slot = (ks * 4 + fq) ^ (row & 7);
        af[mt] = *(const bf16x8*)(Asc + row * 64 + slot * 8);
      }
#pragma unroll
      for (int nt = 0; nt < 4; ++nt) {
        int row = wn * 64 + nt * 16 + fr;
        int slot = (ks * 4 + fq) ^ (row & 7);
        bfr[nt] = *(const bf16x8*)(Bsc + row * 64 + slot * 8);
      }
#pragma unroll
      for (int mt = 0; mt < 4; ++mt)
#pragma unroll
        for (int nt = 0; nt < 4; ++nt)
          acc[mt][nt] = __builtin_amdgcn_mfma_f32_16x16x32_bf16(af[mt], bfr[nt], acc[mt][nt], 0, 0, 0);
    }
    __syncthreads();  // drains this iter's prefetch + WAR-protects buf[cur]
    cur ^= 1;
  }
#undef STAGE

  // epilogue: C/D layout col=lane&15, row=(lane>>4)*4+reg (verified m89/m91)
  const int cr = (lane >> 4) * 4;
  const int cc = lane & 15;
#pragma unroll
  for (int mt = 0; mt < 4; ++mt) {
#pragma unroll
    for (int nt = 0; nt < 4; ++nt) {
#pragma unroll
      for (int r = 0; r < 4; ++r) {
        float v = acc[mt][nt][r];
        long gm = tm + wm * 64 + mt * 16 + cr + r;
        long gn = tn + wn * 64 + nt * 16 + cc;
        if constexpr (EPI == EPI_QK_SPLIT_BF16) {
          // gn in [0,1024) -> Q (Cv,bias) ; [1024,2048) -> K (Cv2,bias2).
          if (gn < 1024) ((u16*)Cv )[gm * (long)ldc + gn]        = f2bf(v + bias [gn]);
          else           ((u16*)Cv2)[gm * (long)ldc + gn - 1024] = f2bf(v + bias2[gn - 1024]);
        } else if constexpr (EPI == EPI_BIAS_ROW_BF16) {
          ((u16*)Cv)[gm * (long)ldc + gn] = f2bf(v + bias[gm]);
        } else if constexpr (EPI == EPI_SCALE_F32) {
          ((float*)Cv)[(long)blockIdx.z * sCz + gm * ldc + gn] = v * scale;
        } else if constexpr (EPI == EPI_BIAS_COL_F32) {
          ((float*)Cv)[gm * (long)ldc + gn] = v + bias[gn];
        } else {  // EPI_RESHAPE_BF16: attn_out [h,s,d]->[s,h*d] faithful reshape
          long rr  = (gn >> 6) * 128 + (gm >> 4);
          long cc2 = ((gm & 15) << 6) + (gn & 63);
          ((u16*)Cv)[(long)blockIdx.z * sCz + rr * 1024 + cc2] = f2bf(v);
        }
      }
    }
  }
}

// ---------------- row softmax: f32 [4096][2048] -> bf16 weights ----------------
__global__ __launch_bounds__(256) void softmax_k(const float* __restrict__ S,
                                                 u16* __restrict__ W) {
  const long row = blockIdx.x;
  const float* src = S + row * 2048;
  u16* dst = W + row * 2048;
  const int t = threadIdx.x, lane = t & 63, wid = t >> 6;

  const float4* sp = (const float4*)(src + t * 8);
  float4 a = sp[0], b = sp[1];
  float m = fmaxf(fmaxf(fmaxf(a.x, a.y), fmaxf(a.z, a.w)),
                  fmaxf(fmaxf(b.x, b.y), fmaxf(b.z, b.w)));
#pragma unroll
  for (int o = 32; o > 0; o >>= 1) m = fmaxf(m, __shfl_xor(m, o));
  __shared__ float redm[4], reds[4];
  if (lane == 0) redm[wid] = m;
  __syncthreads();
  m = fmaxf(fmaxf(redm[0], redm[1]), fmaxf(redm[2], redm[3]));

  float e[8];
  e[0] = __expf(a.x - m); e[1] = __expf(a.y - m);
  e[2] = __expf(a.z - m); e[3] = __expf(a.w - m);
  e[4] = __expf(b.x - m); e[5] = __expf(b.y - m);
  e[6] = __expf(b.z - m); e[7] = __expf(b.w - m);
  float s = ((e[0] + e[1]) + (e[2] + e[3])) + ((e[4] + e[5]) + (e[6] + e[7]));
#pragma unroll
  for (int o = 32; o > 0; o >>= 1) s += __shfl_xor(s, o);
  if (lane == 0) reds[wid] = s;
  __syncthreads();
  s = (reds[0] + reds[1]) + (reds[2] + reds[3]);
  float inv = 1.0f / s;

  uint4 o4;
  o4.x = pack2(e[0] * inv, e[1] * inv);
  o4.y = pack2(e[2] * inv, e[3] * inv);
  o4.z = pack2(e[4] * inv, e[5] * inv);
  o4.w = pack2(e[6] * inv, e[7] * inv);
  *(uint4*)(dst + t * 8) = o4;
}

// ---------------- launch ----------------
extern "C" void kernel_launch(void* const* d_in, const int* in_sizes, int n_in,
                              void* d_out, int out_size, void* d_ws, size_t ws_size,
                              hipStream_t stream) {
  const float* query = (const float*)d_in[0];
  const float* Wq = (const float*)d_in[1];
  const float* bq = (const float*)d_in[2];
  const float* Wk = (const float*)d_in[3];
  const float* bk = (const float*)d_in[4];
  const float* Wv = (const float*)d_in[5];
  const float* bv = (const float*)d_in[6];
  const float* Wo = (const float*)d_in[7];
  const float* bo = (const float*)d_in[8];
  float* out = (float*)d_out;

  char* ws = (char*)d_ws;
  u16*   Xb   = (u16*)(ws);                  // query bf16 [4096][1024]
  u16*   Wqkb = (u16*)(ws + 8388608);        // [2048][1024]  rows 0-1023 Wq, 1024-2047 Wk
  u16*   Wvb  = (u16*)(ws + 12582912);
  u16*   Wob  = (u16*)(ws + 14680064);
  u16*   Qb   = (u16*)(ws + 16777216);       // [4096][1024]
  u16*   Kb   = (u16*)(ws + 25165824);       // [4096][1024]
  u16*   Vtb  = (u16*)(ws + 33554432);       // [1024][4096]  Vt[e][b*2048+s]
  u16*   Rb   = (u16*)(ws + 41943040);       // [2][2048][1024] reshaped attn
  float* Sc   = (float*)(ws + 50331648);     // [2][2048][2048] scores f32
  u16*   Wt   = (u16*)(ws + 83886080);       // [2][2048][2048] weights bf16

  // all f32->bf16 converts in one launch
  cvt_all<<<4096, 256, 0, stream>>>(query, Wq, Wk, Wv, Wo, Xb, Wqkb, Wvb, Wob);

  // [Q|K] = X@[Wq;Wk]^T + [bq;bk]  (M=4096, N=2048, K=1024), split outputs
  gemm_bt<EPI_QK_SPLIT_BF16><<<dim3(32, 16, 1), 256, 0, stream>>>(
      Xb, 0, 1024, Wqkb, 0, 1024, Qb, Kb, 0, 1024, bq, bk, 0.f, 16);
  // Vt = Wv@X^T + bv[row]  (M=1024,N=4096,K=1024) -> V already transposed
  gemm_bt<EPI_BIAS_ROW_BF16><<<dim3(8, 32, 1), 256, 0, stream>>>(
      Wvb, 0, 1024, Xb, 0, 1024, Vtb, nullptr, 0, 4096, bv, nullptr, 0.f, 16);
  // scores = (Q@K^T)/128 per batch (M=2048,N=2048,K=1024)
  gemm_bt<EPI_SCALE_F32><<<dim3(16, 16, 2), 256, 0, stream>>>(
      Qb, 2048L * 1024, 1024, Kb, 2048L * 1024, 1024,
      Sc, nullptr, 2048L * 2048, 2048, nullptr, nullptr, 1.0f / 128.0f, 16);
  // softmax rows -> bf16 weights
  softmax_k<<<4096, 256, 0, stream>>>(Sc, Wt);
  // AO = W@V per batch (M=2048,N=1024,K=2048), epilogue writes faithful reshape
  gemm_bt<EPI_RESHAPE_BF16><<<dim3(16, 8, 2), 256, 0, stream>>>(
      Wt, 2048L * 2048, 2048, Vtb, 2048, 4096,
      Rb, nullptr, 2048L * 1024, 1024, nullptr, nullptr, 0.f, 32);
  // out = R@Wo^T + bo (M=4096,N=1024,K=1024), f32 out
  gemm_bt<EPI_BIAS_COL_F32><<<dim3(32, 8, 1), 256, 0, stream>>>(
      Rb, 0, 1024, Wob, 0, 1024, out, nullptr, 0, 1024, bo, nullptr, 0.f, 16);
}

// Round 4
// 209.453 us; speedup vs baseline: 1.0875x; 1.0875x over previous
//
#include <hip/hip_runtime.h>

typedef unsigned int   u32;
typedef unsigned short u16;
typedef short bf16x8 __attribute__((ext_vector_type(8)));
typedef float f32x4  __attribute__((ext_vector_type(4)));

#define GAS(p) ((const __attribute__((address_space(1))) void*)(p))
#define LAS(p) ((__attribute__((address_space(3))) void*)(p))

__device__ __forceinline__ u16 f2bf(float f) {
  union { float f; u32 u; } v; v.f = f;
  u32 r = v.u + 0x7fffu + ((v.u >> 16) & 1u);
  return (u16)(r >> 16);
}
__device__ __forceinline__ u32 pack2(float a, float b) {
  return (u32)f2bf(a) | ((u32)f2bf(b) << 16);
}

// ---------------- unified f32 -> bf16 convert (all 5 inputs, 1 launch) -------
__global__ __launch_bounds__(256) void cvt_all(
    const float* __restrict__ q,  const float* __restrict__ wq,
    const float* __restrict__ wk, const float* __restrict__ wv,
    const float* __restrict__ wo, u16* __restrict__ xb,
    u16* __restrict__ wqkb, u16* __restrict__ wvb, u16* __restrict__ wob) {
  const int b = blockIdx.x;
  const float* src; u16* dst; long off;
  if (b < 2048)      { src = q;  dst = xb;             off = (long)b * 2048; }
  else if (b < 2560) { src = wq; dst = wqkb;           off = (long)(b - 2048) * 2048; }
  else if (b < 3072) { src = wk; dst = wqkb + 1048576; off = (long)(b - 2560) * 2048; }
  else if (b < 3584) { src = wv; dst = wvb;            off = (long)(b - 3072) * 2048; }
  else               { src = wo; dst = wob;            off = (long)(b - 3584) * 2048; }
  const long i = off + (long)threadIdx.x * 8;
  const float4* xp = (const float4*)(src + i);
  float4 a = xp[0], c = xp[1];
  uint4 o;
  o.x = pack2(a.x, a.y); o.y = pack2(a.z, a.w);
  o.z = pack2(c.x, c.y); o.w = pack2(c.z, c.w);
  *(uint4*)(dst + i) = o;
}

// ---------------- bf16 GEMM body: C = A @ Bt^T (+epilogue) ----------------
// 8 waves (512 thr), 128x128 tile, BK=64, wave grid 2Mx4N, wave-tile 64x32.
// acc[4][2] per wave, mfma_f32_16x16x32_bf16.
// 2-phase dbuf with compile-time buffer indices (K-loop unrolled x2).
// At 512-block grids: 2 blocks/CU -> 4 waves/SIMD; 256-block: 2 waves/SIMD.
// LDS XOR-swizzle (slot ^= row&7) via pre-swizzled global source
// (global_load_lds writes linearly) + swizzled ds_read (guide G4, rule 21).
#define EPI_QK_SPLIT_BF16 0
#define EPI_BIAS_ROW_BF16 1
#define EPI_SCALE_F32     2
#define EPI_BIAS_COL_F32  3
#define EPI_RESHAPE_BF16  4

template <int EPI>
__device__ __forceinline__
void gemm_body(const u16* __restrict__ Ab, int lda,
               const u16* __restrict__ Bb, int ldb,
               void* __restrict__ Cv, void* __restrict__ Cv2, long coff, int ldc,
               const float* __restrict__ bias, const float* __restrict__ bias2,
               float scale, int kTiles, long tm, long tn,
               u16* As0, u16* As1, u16* Bs0, u16* Bs1) {
  const int tid = threadIdx.x, lane = tid & 63, w = tid >> 6;
  const int wm = w >> 2, wn = w & 3;      // wave grid 2x4
  const int rl = lane >> 3;               // row-in-stripe this lane stages
  const int sl = (lane & 7) ^ rl;         // pre-swizzled 16B-slot index
  const int fr = lane & 15, fq = lane >> 4;

  // staging: wave w covers rows [w*16, w*16+16); lane stages rows w*16+rl and +8
  const u16* gA = Ab + (tm + w * 16 + rl) * (long)lda + sl * 8;
  const u16* gB = Bb + (tn + w * 16 + rl) * (long)ldb + sl * 8;

  f32x4 acc[4][2] = {};

#define STAGE(AsX, BsX, kt_)                                                    \
  {                                                                             \
    const int k0_ = (kt_) * 64;                                                 \
    __builtin_amdgcn_global_load_lds(GAS(gA + k0_),            LAS(AsX + w * 1024),       16, 0, 0); \
    __builtin_amdgcn_global_load_lds(GAS(gA + k0_ + 8 * lda),  LAS(AsX + w * 1024 + 512), 16, 0, 0); \
    __builtin_amdgcn_global_load_lds(GAS(gB + k0_),            LAS(BsX + w * 1024),       16, 0, 0); \
    __builtin_amdgcn_global_load_lds(GAS(gB + k0_ + 8 * ldb),  LAS(BsX + w * 1024 + 512), 16, 0, 0); \
  }

#define COMPUTE(AsX, BsX)                                                       \
  {                                                                             \
    _Pragma("unroll")                                                           \
    for (int ks = 0; ks < 2; ++ks) {                                            \
      bf16x8 af[4], bfr[2];                                                     \
      _Pragma("unroll")                                                         \
      for (int mt = 0; mt < 4; ++mt) {                                          \
        int row = wm * 64 + mt * 16 + fr;                                       \
        int slot = (ks * 4 + fq) ^ (fr & 7);                                    \
        af[mt] = *(const bf16x8*)(AsX + row * 64 + slot * 8);                   \
      }                                                                         \
      _Pragma("unroll")                                                         \
      for (int nt = 0; nt < 2; ++nt) {                                          \
        int row = wn * 32 + nt * 16 + fr;                                       \
        int slot = (ks * 4 + fq) ^ (fr & 7);                                    \
        bfr[nt] = *(const bf16x8*)(BsX + row * 64 + slot * 8);                  \
      }                                                                         \
      _Pragma("unroll")                                                         \
      for (int mt = 0; mt < 4; ++mt)                                            \
        _Pragma("unroll")                                                       \
        for (int nt = 0; nt < 2; ++nt)                                          \
          acc[mt][nt] = __builtin_amdgcn_mfma_f32_16x16x32_bf16(af[mt], bfr[nt], acc[mt][nt], 0, 0, 0); \
    }                                                                           \
  }

  STAGE(As0, Bs0, 0);
  __syncthreads();  // buf0 ready (barrier drains vmcnt)
  for (int kt = 0; kt < kTiles; kt += 2) {
    if (kt + 1 < kTiles) STAGE(As1, Bs1, kt + 1);  // prefetch overlaps MFMAs
    COMPUTE(As0, Bs0);
    __syncthreads();
    if (kt + 2 < kTiles) STAGE(As0, Bs0, kt + 2);
    COMPUTE(As1, Bs1);
    __syncthreads();
  }
#undef STAGE
#undef COMPUTE

  // epilogue: C/D layout col=lane&15, row=(lane>>4)*4+reg (verified m89/m91)
  const int cr = (lane >> 4) * 4;
  const int cc = lane & 15;
#pragma unroll
  for (int mt = 0; mt < 4; ++mt) {
#pragma unroll
    for (int nt = 0; nt < 2; ++nt) {
#pragma unroll
      for (int r = 0; r < 4; ++r) {
        float v = acc[mt][nt][r];
        long gm = tm + wm * 64 + mt * 16 + cr + r;
        long gn = tn + wn * 32 + nt * 16 + cc;
        if constexpr (EPI == EPI_QK_SPLIT_BF16) {
          if (gn < 1024) ((u16*)Cv )[gm * (long)ldc + gn]        = f2bf(v + bias [gn]);
          else           ((u16*)Cv2)[gm * (long)ldc + gn - 1024] = f2bf(v + bias2[gn - 1024]);
        } else if constexpr (EPI == EPI_BIAS_ROW_BF16) {
          ((u16*)Cv)[gm * (long)ldc + gn] = f2bf(v + bias[gm]);
        } else if constexpr (EPI == EPI_SCALE_F32) {
          ((float*)Cv)[coff + gm * ldc + gn] = v * scale;
        } else if constexpr (EPI == EPI_BIAS_COL_F32) {
          ((float*)Cv)[gm * (long)ldc + gn] = v + bias[gn];
        } else {  // EPI_RESHAPE_BF16: attn_out [h,s,d]->[s,h*d] faithful reshape
          long rr  = (gn >> 6) * 128 + (gm >> 4);
          long cc2 = ((gm & 15) << 6) + (gn & 63);
          ((u16*)Cv)[coff + rr * 1024 + cc2] = f2bf(v);
        }
      }
    }
  }
}

// merged QK-projection (blocks 0..511) + V-projection (blocks 512..767)
__global__ __launch_bounds__(512, 4)
void k_qkv(const u16* __restrict__ Xb, const u16* __restrict__ Wqkb,
           const u16* __restrict__ Wvb, u16* __restrict__ Qb, u16* __restrict__ Kb,
           u16* __restrict__ Vtb, const float* __restrict__ bq,
           const float* __restrict__ bk, const float* __restrict__ bv) {
  __shared__ __align__(16) u16 As[2][8192], Bs[2][8192];
  const int bid = blockIdx.x;
  if (bid < 512) {
    long tm = (long)(bid & 31) * 128;  // M=4096
    long tn = (long)(bid >> 5) * 128;  // N=2048
    gemm_body<EPI_QK_SPLIT_BF16>(Xb, 1024, Wqkb, 1024, Qb, Kb, 0, 1024,
                                 bq, bk, 0.f, 16, tm, tn, As[0], As[1], Bs[0], Bs[1]);
  } else {
    const int vb = bid - 512;
    long tm = (long)(vb & 7) * 128;    // M=1024
    long tn = (long)(vb >> 3) * 128;   // N=4096
    gemm_body<EPI_BIAS_ROW_BF16>(Wvb, 1024, Xb, 1024, Vtb, nullptr, 0, 4096,
                                 bv, nullptr, 0.f, 16, tm, tn, As[0], As[1], Bs[0], Bs[1]);
  }
}

template <int EPI>
__global__ __launch_bounds__(512, 4)
void k_gemm(const u16* __restrict__ A, long sAz, int lda,
            const u16* __restrict__ Bt, long sBz, int ldb,
            void* __restrict__ Cv, long sCz, int ldc,
            const float* __restrict__ bias, float scale, int kTiles) {
  __shared__ __align__(16) u16 As[2][8192], Bs[2][8192];
  long tm = (long)blockIdx.x * 128, tn = (long)blockIdx.y * 128;
  gemm_body<EPI>(A + (long)blockIdx.z * sAz, lda, Bt + (long)blockIdx.z * sBz, ldb,
                 Cv, nullptr, (long)blockIdx.z * sCz, ldc, bias, nullptr,
                 scale, kTiles, tm, tn, As[0], As[1], Bs[0], Bs[1]);
}

// ---------------- row softmax: f32 [4096][2048] -> bf16 weights ----------------
__global__ __launch_bounds__(256) void softmax_k(const float* __restrict__ S,
                                                 u16* __restrict__ W) {
  const long row = blockIdx.x;
  const float* src = S + row * 2048;
  u16* dst = W + row * 2048;
  const int t = threadIdx.x, lane = t & 63, wid = t >> 6;

  const float4* sp = (const float4*)(src + t * 8);
  float4 a = sp[0], b = sp[1];
  float m = fmaxf(fmaxf(fmaxf(a.x, a.y), fmaxf(a.z, a.w)),
                  fmaxf(fmaxf(b.x, b.y), fmaxf(b.z, b.w)));
#pragma unroll
  for (int o = 32; o > 0; o >>= 1) m = fmaxf(m, __shfl_xor(m, o));
  __shared__ float redm[4], reds[4];
  if (lane == 0) redm[wid] = m;
  __syncthreads();
  m = fmaxf(fmaxf(redm[0], redm[1]), fmaxf(redm[2], redm[3]));

  float e[8];
  e[0] = __expf(a.x - m); e[1] = __expf(a.y - m);
  e[2] = __expf(a.z - m); e[3] = __expf(a.w - m);
  e[4] = __expf(b.x - m); e[5] = __expf(b.y - m);
  e[6] = __expf(b.z - m); e[7] = __expf(b.w - m);
  float s = ((e[0] + e[1]) + (e[2] + e[3])) + ((e[4] + e[5]) + (e[6] + e[7]));
#pragma unroll
  for (int o = 32; o > 0; o >>= 1) s += __shfl_xor(s, o);
  if (lane == 0) reds[wid] = s;
  __syncthreads();
  s = (reds[0] + reds[1]) + (reds[2] + reds[3]);
  float inv = 1.0f / s;

  uint4 o4;
  o4.x = pack2(e[0] * inv, e[1] * inv);
  o4.y = pack2(e[2] * inv, e[3] * inv);
  o4.z = pack2(e[4] * inv, e[5] * inv);
  o4.w = pack2(e[6] * inv, e[7] * inv);
  *(uint4*)(dst + t * 8) = o4;
}

// ---------------- launch ----------------
extern "C" void kernel_launch(void* const* d_in, const int* in_sizes, int n_in,
                              void* d_out, int out_size, void* d_ws, size_t ws_size,
                              hipStream_t stream) {
  const float* query = (const float*)d_in[0];
  const float* Wq = (const float*)d_in[1];
  const float* bq = (const float*)d_in[2];
  const float* Wk = (const float*)d_in[3];
  const float* bk = (const float*)d_in[4];
  const float* Wv = (const float*)d_in[5];
  const float* bv = (const float*)d_in[6];
  const float* Wo = (const float*)d_in[7];
  const float* bo = (const float*)d_in[8];
  float* out = (float*)d_out;

  char* ws = (char*)d_ws;
  u16*   Xb   = (u16*)(ws);                  // query bf16 [4096][1024]
  u16*   Wqkb = (u16*)(ws + 8388608);        // [2048][1024]  rows 0-1023 Wq, 1024-2047 Wk
  u16*   Wvb  = (u16*)(ws + 12582912);
  u16*   Wob  = (u16*)(ws + 14680064);
  u16*   Qb   = (u16*)(ws + 16777216);       // [4096][1024]
  u16*   Kb   = (u16*)(ws + 25165824);       // [4096][1024]
  u16*   Vtb  = (u16*)(ws + 33554432);       // [1024][4096]  Vt[e][b*2048+s]
  u16*   Rb   = (u16*)(ws + 41943040);       // [2][2048][1024] reshaped attn
  float* Sc   = (float*)(ws + 50331648);     // [2][2048][2048] scores f32
  u16*   Wt   = (u16*)(ws + 83886080);       // [2][2048][2048] weights bf16

  // all f32->bf16 converts in one launch
  cvt_all<<<4096, 256, 0, stream>>>(query, Wq, Wk, Wv, Wo, Xb, Wqkb, Wvb, Wob);

  // merged: [Q|K] = X@[Wq;Wk]^T + [bq;bk]  AND  Vt = Wv@X^T + bv  (768 blocks)
  k_qkv<<<768, 512, 0, stream>>>(Xb, Wqkb, Wvb, Qb, Kb, Vtb, bq, bk, bv);

  // scores = (Q@K^T)/128 per batch (M=2048,N=2048,K=1024) -> 512 blocks
  k_gemm<EPI_SCALE_F32><<<dim3(16, 16, 2), 512, 0, stream>>>(
      Qb, 2048L * 1024, 1024, Kb, 2048L * 1024, 1024,
      Sc, 2048L * 2048, 2048, nullptr, 1.0f / 128.0f, 16);
  // softmax rows -> bf16 weights
  softmax_k<<<4096, 256, 0, stream>>>(Sc, Wt);
  // AO = W@V per batch (M=2048,N=1024,K=2048), faithful-reshape epilogue
  k_gemm<EPI_RESHAPE_BF16><<<dim3(16, 8, 2), 512, 0, stream>>>(
      Wt, 2048L * 2048, 2048, Vtb, 2048, 4096,
      Rb, 2048L * 1024, 1024, nullptr, 0.f, 32);
  // out = R@Wo^T + bo (M=4096,N=1024,K=1024), f32 out
  k_gemm<EPI_BIAS_COL_F32><<<dim3(32, 8, 1), 512, 0, stream>>>(
      Rb, 0, 1024, Wob, 0, 1024, out, 0, 1024, bo, 0.f, 16);
}